// Round 4
// baseline (48.289 us; speedup 1.0000x reference)
//
#include <hip/hip_runtime.h>

// RhythmNetLoss: out = mean(|a-b|) + 150 * mean(|x - mean(x)|), x = a[:6].flatten()
// a,b: (8192,4096) fp32. Output: 1 fp32 scalar.

#define N_TOTAL  (8192 * 4096)
#define N_SMOOTH (6 * 4096)
#define LAMBDA_F 150.0f

constexpr int BLOCKS  = 2048;             // main L1 blocks
constexpr int THREADS = 256;
constexpr int N4           = N_TOTAL / 4;            // 8388608 float4
constexpr int F4_PER_BLOCK = N4 / BLOCKS;            // 4096 (64 KiB/input/block)
constexpr int ITERS        = F4_PER_BLOCK / THREADS; // 16 float4/thread
// First NT_BLOCKS block-chunks use non-temporal loads (no L3 fill): 768*128KiB
// = 96 MiB streamed from HBM; remaining 160 MiB stays L3-resident across replays.
constexpr int NT_BLOCKS = 768;

// Native clang vector type — required by __builtin_nontemporal_load.
typedef float vf4 __attribute__((ext_vector_type(4)));

// Block-wide sum + broadcast. NT = blockDim.x (multiple of 64).
template <int NT>
__device__ __forceinline__ float block_reduce_bcast(float v) {
    __shared__ float ws[NT / 64 + 1];
    __syncthreads();  // protect ws across repeated calls
    #pragma unroll
    for (int off = 32; off > 0; off >>= 1) v += __shfl_down(v, off, 64);
    const int lane = threadIdx.x & 63;
    const int wid  = threadIdx.x >> 6;
    if (lane == 0) ws[wid] = v;
    __syncthreads();
    if (threadIdx.x == 0) {
        float s = 0.0f;
        #pragma unroll
        for (int w = 0; w < NT / 64; ++w) s += ws[w];
        ws[NT / 64] = s;
    }
    __syncthreads();
    return ws[NT / 64];
}

__device__ __forceinline__ float abs4(vf4 va, vf4 vb) {
    return fabsf(va.x - vb.x) + fabsf(va.y - vb.y) +
           fabsf(va.z - vb.z) + fabsf(va.w - vb.w);
}

template <bool NTLOAD>
__device__ __forceinline__ vf4 ld4(const vf4* p) {
    if constexpr (NTLOAD) return __builtin_nontemporal_load(p);
    else                  return *p;
}

template <bool NTLOAD>
__device__ __forceinline__ float l1_chunk(const vf4* __restrict__ a,
                                          const vf4* __restrict__ b) {
    const int base = blockIdx.x * F4_PER_BLOCK + threadIdx.x;
    float s0 = 0.0f, s1 = 0.0f, s2 = 0.0f, s3 = 0.0f;
    #pragma unroll
    for (int g = 0; g < ITERS / 4; ++g) {
        const int i0 = base + (g * 4 + 0) * THREADS;
        const int i1 = base + (g * 4 + 1) * THREADS;
        const int i2 = base + (g * 4 + 2) * THREADS;
        const int i3 = base + (g * 4 + 3) * THREADS;
        vf4 a0 = ld4<NTLOAD>(a + i0); vf4 a1 = ld4<NTLOAD>(a + i1);
        vf4 a2 = ld4<NTLOAD>(a + i2); vf4 a3 = ld4<NTLOAD>(a + i3);
        vf4 b0 = ld4<NTLOAD>(b + i0); vf4 b1 = ld4<NTLOAD>(b + i1);
        vf4 b2 = ld4<NTLOAD>(b + i2); vf4 b3 = ld4<NTLOAD>(b + i3);
        s0 += abs4(a0, b0);
        s1 += abs4(a1, b1);
        s2 += abs4(a2, b2);
        s3 += abs4(a3, b3);
    }
    return (s0 + s1) + (s2 + s3);
}

// Kernel A: blocks [0, BLOCKS) compute partial |a-b| sums (first NT_BLOCKS with
// nt loads). Block BLOCKS computes the smooth term's deviation sum in parallel.
__global__ __launch_bounds__(THREADS) void l1_partial_kernel(
    const vf4* __restrict__ a, const vf4* __restrict__ b,
    float* __restrict__ partial) {
    if (blockIdx.x < BLOCKS) {
        float s = (blockIdx.x < NT_BLOCKS) ? l1_chunk<true>(a, b)
                                           : l1_chunk<false>(a, b);
        float bs = block_reduce_bcast<THREADS>(s);
        if (threadIdx.x == 0) partial[blockIdx.x] = bs;
    } else {
        // smooth term: x = first 24576 floats of a (tiny, cached)
        constexpr int NS4 = N_SMOOTH / 4;  // 6144 float4
        float xs = 0.0f;
        for (int i = threadIdx.x; i < NS4; i += THREADS) {
            vf4 v = a[i];
            xs += (v.x + v.y) + (v.z + v.w);
        }
        float x_mean = block_reduce_bcast<THREADS>(xs) / (float)N_SMOOTH;
        float ds = 0.0f;
        for (int i = threadIdx.x; i < NS4; i += THREADS) {
            vf4 v = a[i];
            ds += fabsf(v.x - x_mean) + fabsf(v.y - x_mean) +
                  fabsf(v.z - x_mean) + fabsf(v.w - x_mean);
        }
        float dev_sum = block_reduce_bcast<THREADS>(ds);
        if (threadIdx.x == 0) partial[BLOCKS] = dev_sum;
    }
}

// Kernel B: sum the 2048 partials + combine with the smooth deviation sum.
__global__ __launch_bounds__(THREADS) void finalize_kernel(
    const float* __restrict__ partial, float* __restrict__ out) {
    const vf4* p4 = (const vf4*)partial;
    float s = 0.0f;
    #pragma unroll
    for (int i = threadIdx.x; i < BLOCKS / 4; i += THREADS) {
        vf4 v = p4[i];
        s += (v.x + v.y) + (v.z + v.w);
    }
    float l1_sum = block_reduce_bcast<THREADS>(s);
    if (threadIdx.x == 0) {
        float dev_sum = partial[BLOCKS];
        out[0] = l1_sum / (float)N_TOTAL + LAMBDA_F * (dev_sum / (float)N_SMOOTH);
    }
}

extern "C" void kernel_launch(void* const* d_in, const int* in_sizes, int n_in,
                              void* d_out, int out_size, void* d_ws, size_t ws_size,
                              hipStream_t stream) {
    const float* gru = (const float*)d_in[0];
    const float* tgt = (const float*)d_in[1];
    float* out     = (float*)d_out;
    float* partial = (float*)d_ws;  // (BLOCKS+1) floats

    l1_partial_kernel<<<BLOCKS + 1, THREADS, 0, stream>>>(
        (const vf4*)gru, (const vf4*)tgt, partial);
    finalize_kernel<<<1, THREADS, 0, stream>>>(partial, out);
}